// Round 9
// baseline (47.867 us; speedup 1.0000x reference)
//
#include <hip/hip_runtime.h>
#include <math.h>

#define EPSF 1e-6f
#define CCF  0.01f
#define SQRT_C 0.1f

typedef __attribute__((ext_vector_type(8))) short bf16x8;
typedef __attribute__((ext_vector_type(4))) float f32x4;

__device__ __forceinline__ float wred(float v) {
#pragma unroll
    for (int o = 32; o > 0; o >>= 1) v += __shfl_xor(v, o, 64);
    return v;
}

__device__ __forceinline__ unsigned f2bf1(float x) {
    unsigned u = __builtin_bit_cast(unsigned, x);
    return (u + 0x7FFFu + ((u >> 16) & 1u)) >> 16;   // RTNE
}
__device__ __forceinline__ uint2 pack4(float4 v) {
    uint2 r;
    r.x = f2bf1(v.x) | (f2bf1(v.y) << 16);
    r.y = f2bf1(v.z) | (f2bf1(v.w) << 16);
    return r;
}
__device__ __forceinline__ uint2 pack4s(float4 v, float s) {
    uint2 r;
    r.x = f2bf1(v.x * s) | (f2bf1(v.y * s) << 16);
    r.y = f2bf1(v.z * s) | (f2bf1(v.w * s) << 16);
    return r;
}

// Single self-sufficient kernel: 128 blocks x 1024 threads, 8 batch rows/block.
//   A : gather + log_map -> A[16][256] f32 (rows 0-7 s, 8-15 o)
//   P : per-block rel prep -> s_rel[512], y2s[512] in LDS (512 KB L2-resident read)
//   B : dual f32 GEMV (k-split x2), W read row-major coalesced -> T[16][256]
//   C : exp_map + mobius -> Qbf (bf16 swizzled) + q2s
//   D : MFMA GEMM2, B-fragments built on the fly from f32 rel * s_rel -> epilogue
__global__ __launch_bounds__(1024) void k_solo(const float* __restrict__ E,
                                               const int* __restrict__ trip,
                                               const float* __restrict__ rel,
                                               const float* __restrict__ Ws,
                                               const float* __restrict__ Wo,
                                               const float* __restrict__ rbias,
                                               float* __restrict__ out) {
    __shared__ float A[16][256];
    __shared__ float T[16][256];
    __shared__ unsigned short Qbf[16][256];   // rows 0-7 real, 8-15 garbage (discarded D rows)
    __shared__ float PP[512][2];
    __shared__ float s_rel[512];
    __shared__ float y2s[512];
    __shared__ float q2s[8];

    int b0 = blockIdx.x * 8;
    int t = threadIdx.x;
    int w = t >> 6, lane = t & 63;
    int row16 = lane & 15, g = lane >> 4;

    // ---- Phase A: gather + log_map (16 waves, one row each) ----
    {
        int half = w >> 3, r = w & 7;
        int col = half ? 2 : 0;
        int idx = trip[(b0 + r) * 3 + col];
        idx = max(0, min(idx, 19999));
        float4 v = *(const float4*)(E + (size_t)idx * 256 + lane * 4);
        float ss = v.x * v.x;
        ss = fmaf(v.y, v.y, ss);
        ss = fmaf(v.z, v.z, ss);
        ss = fmaf(v.w, v.w, ss);
        ss = wred(ss);
        float n = fmaxf(sqrtf(ss), EPSF);
        float arg = fminf(SQRT_C * n, 1.f - 1e-5f);
        float s = atanhf(arg) / (SQRT_C * n);
        v.x *= s; v.y *= s; v.z *= s; v.w *= s;
        *(float4*)&A[w][lane * 4] = v;
    }

    // ---- Phase P1: rel row partial sumsq (2 threads per row) ----
    {
        int r = t >> 1, h = t & 1;
        const float* p = rel + (size_t)r * 256 + h * 128;
        float ss = 0.f;
#pragma unroll 8
        for (int j = 0; j < 32; ++j) {
            float4 v = *(const float4*)(p + j * 4);
            ss = fmaf(v.x, v.x, ss);
            ss = fmaf(v.y, v.y, ss);
            ss = fmaf(v.z, v.z, ss);
            ss = fmaf(v.w, v.w, ss);
        }
        PP[r][h] = ss;
    }
    __syncthreads();

    // ---- Phase P2: exp_map scale + y2 for all 512 rel rows ----
    if (t < 512) {
        float ss = PP[t][0] + PP[t][1];
        float n = fmaxf(sqrtf(ss), EPSF);
        float s = tanhf(SQRT_C * n) / (SQRT_C * n);
        s_rel[t] = s;
        y2s[t] = s * s * ss;
    }

    // ---- Phase B: dual f32 GEMV, k-split (4 groups of 256 threads) ----
    {
        int gq = t >> 8;           // 0..3
        int halfsel = gq & 1;      // 0: s rows @ Ws, 1: o rows @ Wo
        int kh = gq >> 1;          // k half
        int c = t & 255;
        int r0 = halfsel * 8;
        const float* __restrict__ W = halfsel ? Wo : Ws;
        int kb = kh * 128;
        float acc[8] = {};
#pragma unroll 2
        for (int k = 0; k < 128; k += 4) {
            int kk = kb + k;
            float4 a0 = *(const float4*)&A[r0 + 0][kk];
            float4 a1 = *(const float4*)&A[r0 + 1][kk];
            float4 a2 = *(const float4*)&A[r0 + 2][kk];
            float4 a3 = *(const float4*)&A[r0 + 3][kk];
            float4 a4 = *(const float4*)&A[r0 + 4][kk];
            float4 a5 = *(const float4*)&A[r0 + 5][kk];
            float4 a6 = *(const float4*)&A[r0 + 6][kk];
            float4 a7 = *(const float4*)&A[r0 + 7][kk];
            float w0 = W[(size_t)(kk + 0) * 256 + c];
            float w1 = W[(size_t)(kk + 1) * 256 + c];
            float w2 = W[(size_t)(kk + 2) * 256 + c];
            float w3 = W[(size_t)(kk + 3) * 256 + c];
            acc[0] = fmaf(a0.w, w3, fmaf(a0.z, w2, fmaf(a0.y, w1, fmaf(a0.x, w0, acc[0]))));
            acc[1] = fmaf(a1.w, w3, fmaf(a1.z, w2, fmaf(a1.y, w1, fmaf(a1.x, w0, acc[1]))));
            acc[2] = fmaf(a2.w, w3, fmaf(a2.z, w2, fmaf(a2.y, w1, fmaf(a2.x, w0, acc[2]))));
            acc[3] = fmaf(a3.w, w3, fmaf(a3.z, w2, fmaf(a3.y, w1, fmaf(a3.x, w0, acc[3]))));
            acc[4] = fmaf(a4.w, w3, fmaf(a4.z, w2, fmaf(a4.y, w1, fmaf(a4.x, w0, acc[4]))));
            acc[5] = fmaf(a5.w, w3, fmaf(a5.z, w2, fmaf(a5.y, w1, fmaf(a5.x, w0, acc[5]))));
            acc[6] = fmaf(a6.w, w3, fmaf(a6.z, w2, fmaf(a6.y, w1, fmaf(a6.x, w0, acc[6]))));
            acc[7] = fmaf(a7.w, w3, fmaf(a7.z, w2, fmaf(a7.y, w1, fmaf(a7.x, w0, acc[7]))));
        }
        if (kh) {
#pragma unroll
            for (int m = 0; m < 8; ++m) T[r0 + m][c] = acc[m];
        }
        __syncthreads();
        if (!kh) {
#pragma unroll
            for (int m = 0; m < 8; ++m) T[r0 + m][c] += acc[m];
        }
    }
    __syncthreads();

    // ---- Phase C: exp_map + mobius_add(-s_h, o_h): waves 0-7 ----
    if (w < 8) {
        float4 sv = *(const float4*)&T[w][lane * 4];
        float4 ov = *(const float4*)&T[8 + w][lane * 4];
        float sss = sv.x * sv.x, sso = ov.x * ov.x, sdot = sv.x * ov.x;
        sss = fmaf(sv.y, sv.y, sss); sso = fmaf(ov.y, ov.y, sso); sdot = fmaf(sv.y, ov.y, sdot);
        sss = fmaf(sv.z, sv.z, sss); sso = fmaf(ov.z, ov.z, sso); sdot = fmaf(sv.z, ov.z, sdot);
        sss = fmaf(sv.w, sv.w, sss); sso = fmaf(ov.w, ov.w, sso); sdot = fmaf(sv.w, ov.w, sdot);
        sss = wred(sss); sso = wred(sso); sdot = wred(sdot);
        float ns = fmaxf(sqrtf(sss), EPSF);
        float no = fmaxf(sqrtf(sso), EPSF);
        float scs = tanhf(SQRT_C * ns) / (SQRT_C * ns);
        float sco = tanhf(SQRT_C * no) / (SQRT_C * no);
        float x2 = scs * scs * sss;
        float yy2 = sco * sco * sso;
        float xy = -scs * sco * sdot;
        float a1 = 1.f + 2.f * CCF * xy + CCF * yy2;
        float b1 = 1.f - CCF * x2;
        float den = 1.f + 2.f * CCF * xy + CCF * CCF * x2 * yy2 + EPSF;
        float rden = 1.f / den;
        float4 qv;
        qv.x = (a1 * (-scs * sv.x) + b1 * (sco * ov.x)) * rden;
        qv.y = (a1 * (-scs * sv.y) + b1 * (sco * ov.y)) * rden;
        qv.z = (a1 * (-scs * sv.z) + b1 * (sco * ov.z)) * rden;
        qv.w = (a1 * (-scs * sv.w) + b1 * (sco * ov.w)) * rden;
        float qq = qv.x * qv.x;
        qq = fmaf(qv.y, qv.y, qq);
        qq = fmaf(qv.z, qv.z, qq);
        qq = fmaf(qv.w, qv.w, qq);
        qq = wred(qq);
        char* qb = (char*)&Qbf[0][0];
        *(uint2*)(qb + w * 512 + ((lane * 8) ^ (w << 4))) = pack4(qv);
        if (lane == 0) q2s[w] = qq;
    }
    __syncthreads();

    // ---- Phase D: MFMA GEMM2, B-fragments on the fly from f32 rel ----
    {
        int nb = w * 32;
        const char* Qbase = (const char*)&Qbf[0][0];
        bf16x8 qf[8];
#pragma unroll
        for (int kt = 0; kt < 8; ++kt)
            qf[kt] = *(const bf16x8*)(Qbase + row16 * 512 + ((kt * 64 + g * 16) ^ ((row16 & 7) << 4)));
        float s0 = s_rel[nb + row16];
        float s1 = s_rel[nb + 16 + row16];
        const float* p0 = rel + (size_t)(nb + row16) * 256 + g * 8;
        const float* p1 = rel + (size_t)(nb + 16 + row16) * 256 + g * 8;
        f32x4 acc0 = {0.f, 0.f, 0.f, 0.f};
        f32x4 acc1 = {0.f, 0.f, 0.f, 0.f};
#pragma unroll
        for (int kt = 0; kt < 8; ++kt) {
            union { bf16x8 v; uint2 u[2]; } ub0, ub1;
            ub0.u[0] = pack4s(*(const float4*)(p0 + kt * 32), s0);
            ub0.u[1] = pack4s(*(const float4*)(p0 + kt * 32 + 4), s0);
            ub1.u[0] = pack4s(*(const float4*)(p1 + kt * 32), s1);
            ub1.u[1] = pack4s(*(const float4*)(p1 + kt * 32 + 4), s1);
            acc0 = __builtin_amdgcn_mfma_f32_16x16x32_bf16(qf[kt], ub0.v, acc0, 0, 0, 0);
            acc1 = __builtin_amdgcn_mfma_f32_16x16x32_bf16(qf[kt], ub1.v, acc1, 0, 0, 0);
        }
        if (lane < 32) {
#pragma unroll
            for (int tt = 0; tt < 2; ++tt) {
                int r = nb + tt * 16 + row16;
                f32x4 a = tt ? acc1 : acc0;
                float y2r = y2s[r];
                float rb = rbias[r];
#pragma unroll
                for (int i = 0; i < 4; ++i) {
                    int m = g * 4 + i;   // 0..7
                    float xy = -a[i];    // dot(-query, rel_h)
                    float x2 = q2s[m];
                    float a1 = 1.f + 2.f * CCF * xy + CCF * y2r;
                    float b1 = 1.f - CCF * x2;
                    float den = 1.f + 2.f * CCF * xy + CCF * CCF * x2 * y2r + EPSF;
                    float num2 = a1 * a1 * x2 + 2.f * a1 * b1 * xy + b1 * b1 * y2r;
                    out[(size_t)(b0 + m) * 512 + r] = -(num2 / (den * den)) + rb;
                }
            }
        }
    }
}

extern "C" void kernel_launch(void* const* d_in, const int* in_sizes, int n_in,
                              void* d_out, int out_size, void* d_ws, size_t ws_size,
                              hipStream_t stream) {
    const float* E = (const float*)d_in[0];          // 20000 x 256
    const float* rel = (const float*)d_in[1];        // 512 x 256
    const int* trip = (const int*)d_in[2];           // 1024 x 3 (int32)
    const float* Ws = (const float*)d_in[3];         // 256 x 256
    const float* Wo = (const float*)d_in[4];         // 256 x 256
    const float* rbias = (const float*)d_in[5];      // 512
    float* out = (float*)d_out;                      // 1024 x 512

    k_solo<<<128, 1024, 0, stream>>>(E, trip, rel, Ws, Wo, rbias, out);
}

// Round 10
// 22.165 us; speedup vs baseline: 2.1596x; 2.1596x over previous
//
#include <hip/hip_runtime.h>
#include <math.h>

#define EPSF 1e-6f
#define CCF  0.01f
#define SQRT_C 0.1f

typedef __attribute__((ext_vector_type(8))) short bf16x8;
typedef __attribute__((ext_vector_type(4))) float f32x4;

__device__ __forceinline__ float wred(float v) {
#pragma unroll
    for (int o = 32; o > 0; o >>= 1) v += __shfl_xor(v, o, 64);
    return v;
}
__device__ __forceinline__ unsigned f2bf1(float x) {
    unsigned u = __builtin_bit_cast(unsigned, x);
    return (u + 0x7FFFu + ((u >> 16) & 1u)) >> 16;   // RTNE
}
__device__ __forceinline__ uint2 pack4(float4 v) {
    uint2 r;
    r.x = f2bf1(v.x) | (f2bf1(v.y) << 16);
    r.y = f2bf1(v.z) | (f2bf1(v.w) << 16);
    return r;
}

// K1: blocks 0-127 gather+log -> xs bf16 [2048][256]
//     blocks 128-143 rel exp_map -> relbf bf16 [512][256] + y2 f32
//     blocks 144-175 W transpose -> WT bf16 [2][256 n][256 k]
__global__ __launch_bounds__(256) void k1(const float* __restrict__ E,
                                          const int* __restrict__ trip,
                                          const float* __restrict__ rel,
                                          const float* __restrict__ Ws,
                                          const float* __restrict__ Wo,
                                          unsigned short* __restrict__ xs,
                                          unsigned short* __restrict__ relbf,
                                          float* __restrict__ y2,
                                          unsigned short* __restrict__ WT) {
    __shared__ float tile[64][65];
    int blk = blockIdx.x;
    int t = threadIdx.x, w = t >> 6, lane = t & 63;
    if (blk < 128) {
#pragma unroll
        for (int rr = 0; rr < 4; ++rr) {
            int z = blk * 16 + rr * 4 + w;       // 0..2047
            int b = z & 1023;
            int col = (z >> 10) ? 2 : 0;
            int idx = trip[b * 3 + col];
            idx = max(0, min(idx, 19999));
            float4 v = *(const float4*)(E + (size_t)idx * 256 + lane * 4);
            float ss = v.x * v.x;
            ss = fmaf(v.y, v.y, ss);
            ss = fmaf(v.z, v.z, ss);
            ss = fmaf(v.w, v.w, ss);
            ss = wred(ss);
            float n = fmaxf(sqrtf(ss), EPSF);
            float arg = fminf(SQRT_C * n, 1.f - 1e-5f);
            float s = atanhf(arg) / (SQRT_C * n);
            v.x *= s; v.y *= s; v.z *= s; v.w *= s;
            *(uint2*)(xs + (size_t)z * 256 + lane * 4) = pack4(v);
        }
    } else if (blk < 144) {
#pragma unroll
        for (int rr = 0; rr < 8; ++rr) {
            int r = (blk - 128) * 32 + rr * 4 + w;   // 0..511
            float4 v = *(const float4*)(rel + (size_t)r * 256 + lane * 4);
            float ss = v.x * v.x;
            ss = fmaf(v.y, v.y, ss);
            ss = fmaf(v.z, v.z, ss);
            ss = fmaf(v.w, v.w, ss);
            ss = wred(ss);
            float n = fmaxf(sqrtf(ss), EPSF);
            float s = tanhf(SQRT_C * n) / (SQRT_C * n);
            v.x *= s; v.y *= s; v.z *= s; v.w *= s;
            *(uint2*)(relbf + (size_t)r * 256 + lane * 4) = pack4(v);
            if (lane == 0) y2[r] = s * s * ss;
        }
    } else {
        int blk2 = blk - 144;          // 0..31
        int mat = blk2 >> 4;           // 0: Ws, 1: Wo
        int tl = blk2 & 15;
        int k0 = (tl >> 2) * 64, n0 = (tl & 3) * 64;
        const float* __restrict__ W = mat ? Wo : Ws;
#pragma unroll 4
        for (int p = 0; p < 16; ++p) {
            int i = p * 4 + w;
            tile[i][lane] = W[(size_t)(k0 + i) * 256 + n0 + lane];
        }
        __syncthreads();
#pragma unroll 4
        for (int p = 0; p < 16; ++p) {
            int n = p * 4 + w;
            WT[(size_t)mat * 65536 + (size_t)(n0 + n) * 256 + k0 + lane] =
                (unsigned short)f2bf1(tile[lane][n]);
        }
    }
}

// K2: GEMM1  T[2048][256] = xs @ (Ws|Wo).  2D tiles 32x64, 256 blocks x 256 thr.
__global__ __launch_bounds__(256) void k2(const unsigned short* __restrict__ xs,
                                          const unsigned short* __restrict__ WT,
                                          float* __restrict__ T) {
    __shared__ unsigned short Al[32 * 256];
    __shared__ unsigned short Bl[64 * 256];
    int bid = blockIdx.x;
    int M0 = (bid >> 2) * 32, N0 = (bid & 3) * 64;
    int mat = (M0 >= 1024);
    int t = threadIdx.x, w = t >> 6, lane = t & 63;
    int row16 = lane & 15, g = lane >> 4;
    char* Ab = (char*)Al;
    char* Bb = (char*)Bl;
#pragma unroll
    for (int i = 0; i < 4; ++i) {
        int L = i * 256 + t, r = L >> 5, c = L & 31;
        bf16x8 v = *(const bf16x8*)(xs + (size_t)(M0 + r) * 256 + c * 8);
        *(bf16x8*)(Ab + r * 512 + ((c * 16) ^ ((r & 7) << 4))) = v;
    }
#pragma unroll
    for (int i = 0; i < 8; ++i) {
        int L = i * 256 + t, r = L >> 5, c = L & 31;
        bf16x8 v = *(const bf16x8*)(WT + (size_t)mat * 65536 + (size_t)(N0 + r) * 256 + c * 8);
        *(bf16x8*)(Bb + r * 512 + ((c * 16) ^ ((r & 7) << 4))) = v;
    }
    __syncthreads();
    int wm = (w >> 1) * 16, wn = (w & 1) * 32;
    f32x4 acc0 = {0.f, 0.f, 0.f, 0.f};
    f32x4 acc1 = {0.f, 0.f, 0.f, 0.f};
    int mr = wm + row16, n0r = wn + row16, n1r = wn + 16 + row16;
#pragma unroll
    for (int kt = 0; kt < 8; ++kt) {
        bf16x8 a  = *(const bf16x8*)(Ab + mr * 512 + ((kt * 64 + g * 16) ^ ((mr & 7) << 4)));
        bf16x8 b0 = *(const bf16x8*)(Bb + n0r * 512 + ((kt * 64 + g * 16) ^ ((n0r & 7) << 4)));
        bf16x8 b1 = *(const bf16x8*)(Bb + n1r * 512 + ((kt * 64 + g * 16) ^ ((n1r & 7) << 4)));
        acc0 = __builtin_amdgcn_mfma_f32_16x16x32_bf16(a, b0, acc0, 0, 0, 0);
        acc1 = __builtin_amdgcn_mfma_f32_16x16x32_bf16(a, b1, acc1, 0, 0, 0);
    }
#pragma unroll
    for (int i = 0; i < 4; ++i) {
        int m = M0 + wm + g * 4 + i;
        T[(size_t)m * 256 + N0 + wn + row16]      = acc0[i];
        T[(size_t)m * 256 + N0 + wn + 16 + row16] = acc1[i];
    }
}

// K3: mobius -> query bf16 [1024][256] + q2. 128 blocks x 512 thr (wave = 1 pair).
__global__ __launch_bounds__(512) void k3(const float* __restrict__ T,
                                          unsigned short* __restrict__ qbf,
                                          float* __restrict__ q2) {
    int t = threadIdx.x, w = t >> 6, lane = t & 63;
    int b = blockIdx.x * 8 + w;
    float4 sv = *(const float4*)(T + (size_t)b * 256 + lane * 4);
    float4 ov = *(const float4*)(T + (size_t)(1024 + b) * 256 + lane * 4);
    float sss = sv.x * sv.x, sso = ov.x * ov.x, sdot = sv.x * ov.x;
    sss = fmaf(sv.y, sv.y, sss); sso = fmaf(ov.y, ov.y, sso); sdot = fmaf(sv.y, ov.y, sdot);
    sss = fmaf(sv.z, sv.z, sss); sso = fmaf(ov.z, ov.z, sso); sdot = fmaf(sv.z, ov.z, sdot);
    sss = fmaf(sv.w, sv.w, sss); sso = fmaf(ov.w, ov.w, sso); sdot = fmaf(sv.w, ov.w, sdot);
    sss = wred(sss); sso = wred(sso); sdot = wred(sdot);
    float ns = fmaxf(sqrtf(sss), EPSF);
    float no = fmaxf(sqrtf(sso), EPSF);
    float scs = tanhf(SQRT_C * ns) / (SQRT_C * ns);
    float sco = tanhf(SQRT_C * no) / (SQRT_C * no);
    float x2 = scs * scs * sss;
    float yy2 = sco * sco * sso;
    float xy = -scs * sco * sdot;
    float a1 = 1.f + 2.f * CCF * xy + CCF * yy2;
    float b1 = 1.f - CCF * x2;
    float den = 1.f + 2.f * CCF * xy + CCF * CCF * x2 * yy2 + EPSF;
    float rden = 1.f / den;
    float4 qv;
    qv.x = (a1 * (-scs * sv.x) + b1 * (sco * ov.x)) * rden;
    qv.y = (a1 * (-scs * sv.y) + b1 * (sco * ov.y)) * rden;
    qv.z = (a1 * (-scs * sv.z) + b1 * (sco * ov.z)) * rden;
    qv.w = (a1 * (-scs * sv.w) + b1 * (sco * ov.w)) * rden;
    float qq = qv.x * qv.x;
    qq = fmaf(qv.y, qv.y, qq);
    qq = fmaf(qv.z, qv.z, qq);
    qq = fmaf(qv.w, qv.w, qq);
    qq = wred(qq);
    *(uint2*)(qbf + (size_t)b * 256 + lane * 4) = pack4(qv);
    if (lane == 0) q2[b] = qq;
}

// K4: GEMM2 (query . rel_h) 2D-tiled 32x64 + closed-form epilogue. 256 blocks.
__global__ __launch_bounds__(256) void k4(const unsigned short* __restrict__ qbf,
                                          const unsigned short* __restrict__ relbf,
                                          const float* __restrict__ q2,
                                          const float* __restrict__ y2,
                                          const float* __restrict__ rbias,
                                          float* __restrict__ out) {
    __shared__ unsigned short Al[32 * 256];
    __shared__ unsigned short Bl[64 * 256];
    __shared__ float q2l[32], y2l[64], rbl[64];
    int bid = blockIdx.x;
    int M0 = (bid >> 3) * 32, N0 = (bid & 7) * 64;
    int t = threadIdx.x, w = t >> 6, lane = t & 63;
    int row16 = lane & 15, g = lane >> 4;
    char* Ab = (char*)Al;
    char* Bb = (char*)Bl;
#pragma unroll
    for (int i = 0; i < 4; ++i) {
        int L = i * 256 + t, r = L >> 5, c = L & 31;
        bf16x8 v = *(const bf16x8*)(qbf + (size_t)(M0 + r) * 256 + c * 8);
        *(bf16x8*)(Ab + r * 512 + ((c * 16) ^ ((r & 7) << 4))) = v;
    }
#pragma unroll
    for (int i = 0; i < 8; ++i) {
        int L = i * 256 + t, r = L >> 5, c = L & 31;
        bf16x8 v = *(const bf16x8*)(relbf + (size_t)(N0 + r) * 256 + c * 8);
        *(bf16x8*)(Bb + r * 512 + ((c * 16) ^ ((r & 7) << 4))) = v;
    }
    if (t < 32) q2l[t] = q2[M0 + t];
    else if (t < 96) y2l[t - 32] = y2[N0 + t - 32];
    else if (t < 160) rbl[t - 96] = rbias[N0 + t - 96];
    __syncthreads();
    int wm = (w >> 1) * 16, wn = (w & 1) * 32;
    f32x4 acc0 = {0.f, 0.f, 0.f, 0.f};
    f32x4 acc1 = {0.f, 0.f, 0.f, 0.f};
    int mr = wm + row16, n0r = wn + row16, n1r = wn + 16 + row16;
#pragma unroll
    for (int kt = 0; kt < 8; ++kt) {
        bf16x8 a  = *(const bf16x8*)(Ab + mr * 512 + ((kt * 64 + g * 16) ^ ((mr & 7) << 4)));
        bf16x8 b0 = *(const bf16x8*)(Bb + n0r * 512 + ((kt * 64 + g * 16) ^ ((n0r & 7) << 4)));
        bf16x8 b1 = *(const bf16x8*)(Bb + n1r * 512 + ((kt * 64 + g * 16) ^ ((n1r & 7) << 4)));
        acc0 = __builtin_amdgcn_mfma_f32_16x16x32_bf16(a, b0, acc0, 0, 0, 0);
        acc1 = __builtin_amdgcn_mfma_f32_16x16x32_bf16(a, b1, acc1, 0, 0, 0);
    }
#pragma unroll
    for (int tt = 0; tt < 2; ++tt) {
        int rloc = wn + tt * 16 + row16;
        int r = N0 + rloc;
        f32x4 a = tt ? acc1 : acc0;
        float y2r = y2l[rloc];
        float rb = rbl[rloc];
#pragma unroll
        for (int i = 0; i < 4; ++i) {
            int mloc = wm + g * 4 + i;
            float xy = -a[i];          // dot(-query, rel_h)
            float x2 = q2l[mloc];
            float a1 = 1.f + 2.f * CCF * xy + CCF * y2r;
            float b1 = 1.f - CCF * x2;
            float den = 1.f + 2.f * CCF * xy + CCF * CCF * x2 * y2r + EPSF;
            float num2 = a1 * a1 * x2 + 2.f * a1 * b1 * xy + b1 * b1 * y2r;
            out[(size_t)(M0 + mloc) * 512 + r] = -(num2 / (den * den)) + rb;
        }
    }
}

extern "C" void kernel_launch(void* const* d_in, const int* in_sizes, int n_in,
                              void* d_out, int out_size, void* d_ws, size_t ws_size,
                              hipStream_t stream) {
    const float* E = (const float*)d_in[0];          // 20000 x 256
    const float* rel = (const float*)d_in[1];        // 512 x 256
    const int* trip = (const int*)d_in[2];           // 1024 x 3 (int32)
    const float* Ws = (const float*)d_in[3];         // 256 x 256
    const float* Wo = (const float*)d_in[4];         // 256 x 256
    const float* rbias = (const float*)d_in[5];      // 512
    float* out = (float*)d_out;                      // 1024 x 512

    char* p = (char*)d_ws;
    unsigned short* xs    = (unsigned short*)p;  p += (size_t)2048 * 256 * 2;  // 1 MB
    float*          T     = (float*)p;           p += (size_t)2048 * 256 * 4;  // 2 MB
    unsigned short* qbf   = (unsigned short*)p;  p += (size_t)1024 * 256 * 2;  // 512 KB
    float*          q2    = (float*)p;           p += 4096;
    unsigned short* relbf = (unsigned short*)p;  p += (size_t)512 * 256 * 2;   // 256 KB
    float*          y2    = (float*)p;           p += 2048;
    unsigned short* WT    = (unsigned short*)p;  p += (size_t)2 * 256 * 256 * 2; // 256 KB

    k1<<<176, 256, 0, stream>>>(E, trip, rel, Ws, Wo, xs, relbf, y2, WT);
    k2<<<256, 256, 0, stream>>>(xs, WT, T);
    k3<<<128, 512, 0, stream>>>(T, qbf, q2);
    k4<<<256, 256, 0, stream>>>(qbf, relbf, q2, y2, rbias, out);
}